// Round 8
// baseline (15938.858 us; speedup 1.0000x reference)
//
#include <hip/hip_runtime.h>
#include <cstdint>
#include <cstddef>

// Problem constants
#define B_  4096
#define H_  300
#define T_  43
#define NC_ 80
#define HP  320       // padded hidden/input dim (300 -> 320)
#define ND  1280      // padded 4H per direction
#define TR  304       // hs per-t row length in f16 (300 + 4 zero pad)
#define SB2 (T_ * TR) // hs per-(d,b) stride in f16 = 13072
#define CHB 20480     // weight chunk, f16 units (40 mtiles x 512)
#define SMEM_BYTES 102400  // wbuf 2x40960 + hbuf 20480

typedef _Float16 f16;
typedef _Float16 half8 __attribute__((ext_vector_type(8)));
typedef _Float16 half4 __attribute__((ext_vector_type(4)));
typedef float    f32x4 __attribute__((ext_vector_type(4)));

__device__ __forceinline__ void gl_lds16(const void* g, void* l) {
  __builtin_amdgcn_global_load_lds(
      (const __attribute__((address_space(1))) void*)g,
      (__attribute__((address_space(3))) void*)l, 16, 0, 0);
}
__device__ __forceinline__ float sigmoid_(float x) {
  return 1.f / (1.f + __expf(-x));
}
__device__ __forceinline__ float tanh_fast(float x) {
  x = fminf(fmaxf(x, -15.f), 15.f);
  float e = __expf(2.f * x);
  return (e - 1.f) / (e + 1.f);
}

// ---------------------------------------------------------------------------
// Weight packing, FRAG-LINEAR: Wp laid out as
//   [d][kc 0..19][half 0..1][mt 0..39][lane 0..63][e 0..7]  (f16)
// lane = q*16+lr encodes frag position: gate row = half*640+mt*16+lr,
// k = kc*32+q*8+e. Gate rows are gate-interleaved n = 4*jh+g (i,f,g,o);
// k<320 = w_ih, k>=320 = w_hh; zeros for jh>=300 or k-part>=300.
// A linear global_load_lds stream of one chunk lands in LDS exactly in
// MFMA A-fragment order. bias[d*1280 + 4*jh+g] = b_ih+b_hh.
// ---------------------------------------------------------------------------
__global__ void prep_weights(const float* __restrict__ w_ih,
                             const float* __restrict__ w_hh,
                             const float* __restrict__ b_ih,
                             const float* __restrict__ b_hh,
                             f16* __restrict__ Wp, float* __restrict__ bias) {
  long idx = (long)blockIdx.x * 256 + threadIdx.x;
  const long total = 2L * 20 * 2 * 40 * 512;  // 1,638,400
  if (idx < total) {
    long r = idx;
    int e = r & 7;          r >>= 3;
    int lane = r & 63;      r >>= 6;
    int mt = (int)(r % 40); r /= 40;
    int half = (int)(r & 1); r >>= 1;
    int kc = (int)(r % 20); r /= 20;
    int d = (int)r;
    int lr = lane & 15, q = lane >> 4;
    int n = half * 640 + mt * 16 + lr;
    int k = kc * 32 + q * 8 + e;
    int jh = n >> 2, g = n & 3;
    float v = 0.f;
    if (jh < H_) {
      if (k < HP) {
        if (k < H_) v = w_ih[((size_t)d * 4 * H_ + g * H_ + jh) * H_ + k];
      } else {
        int kk = k - HP;
        if (kk < H_) v = w_hh[((size_t)d * 4 * H_ + g * H_ + jh) * H_ + kk];
      }
    }
    Wp[idx] = (f16)v;
  }
  if (idx < 2 * ND) {
    int d = (int)(idx / ND), n = (int)(idx % ND);
    int jh = n >> 2, g = n & 3;
    float v = 0.f;
    if (jh < H_)
      v = b_ih[d * 4 * H_ + g * H_ + jh] + b_hh[d * 4 * H_ + g * H_ + jh];
    bias[idx] = v;
  }
}

// ---------------------------------------------------------------------------
// x [B,H,T] fp32 -> xT[t*B+b][k] f16, k padded to 320 with zeros.
// ---------------------------------------------------------------------------
__global__ void prep_xT(const float* __restrict__ x, f16* __restrict__ xT) {
  __shared__ float tile[64][44];
  int b = blockIdx.x, ch = blockIdx.y;
  int h0 = ch * 64;
  for (int idx = threadIdx.x; idx < 64 * T_; idx += 256) {
    int hh = idx / T_, t = idx % T_;
    float v = 0.f;
    if (h0 + hh < H_) v = x[((size_t)b * H_ + h0 + hh) * T_ + t];
    tile[hh][t] = v;
  }
  __syncthreads();
  for (int idx = threadIdx.x; idx < 64 * T_; idx += 256) {
    int t = idx / 64, hh = idx % 64;
    xT[((size_t)t * B_ + b) * HP + h0 + hh] = (f16)tile[hh][t];
  }
}

// ---------------------------------------------------------------------------
// Persistent LSTM, batch-partitioned: block = (direction d, 32 batch rows).
// ENTIRE recurrence is block-private: h lives in LDS (frag-order) across all
// 43 steps -> no inter-block sync, no coherence traffic. Per step, each block
// computes z[1280 gates][32 b] = Wc_d @ [x_t | h]^T via 40 double-buffered
// weight chunks (K=32 x 640 gates, frag-linear global_load_lds streams).
// Wave w owns gates [w*320, w*320+320): acc[20][2] f32x4, lane's 4 regs =
// 4 gates (i,f,g,o) of one jh (proven epilogue). c block-private in global
// ([d][jh][B], L2-hot). hs written coalesced (consumed by attn post-kernel).
// grid 256 blocks (d = id&1 -> XCD-swizzled: each XCD caches ONE direction's
// 1.6 MB weights in its 4 MB L2), 1 block/CU.
// ---------------------------------------------------------------------------
__global__ __launch_bounds__(256, 1) void lstm_persist(
    const f16* __restrict__ Wp,     // frag-linear, see prep_weights
    const float* __restrict__ bias, // [2][1280]
    const f16* __restrict__ xT,     // [43][4096][320]
    float* __restrict__ c,          // [2][300][4096], memset 0
    f16* __restrict__ hs)           // [2][4096][43][304]
{
  extern __shared__ __attribute__((aligned(16))) char smem[];
  f16* wbuf = (f16*)smem;                 // 2 x 20480 f16 (81920 B)
  f16* hbuf = (f16*)(smem + 81920);       // 10240 f16: [kr][j][lane][8]

  const int tid = threadIdx.x;
  const int w = tid >> 6, lane = tid & 63;
  const int lr = lane & 15, lq = lane >> 4;
  const int id = blockIdx.x;
  const int d = id & 1, bt = id >> 1;     // consecutive ids alternate XCD & d

  const f16* Wd = Wp + (size_t)d * 40 * CHB;
  float* cb = c + (size_t)d * H_ * B_ + bt * 32;

  // zero hbuf (h(-1) = 0; jh>=300 slots stay zero forever)
  for (int i = tid; i < 5120; i += 256) ((uint32_t*)hbuf)[i] = 0u;

  for (int t = 0; t < T_; ++t) {
    // prologue: stage chunk 0 into wbuf[0] (wave w stages its 10 m-tiles)
    {
      const f16* src = Wd;
#pragma unroll
      for (int s = 0; s < 10; ++s) {
        const int mt = w * 10 + s;
        gl_lds16(src + mt * 512 + lane * 8, wbuf + mt * 512);
      }
    }

    f32x4 acc[20][2];
#pragma unroll
    for (int i = 0; i < 20; ++i) {
      acc[i][0] = (f32x4){0.f, 0.f, 0.f, 0.f};
      acc[i][1] = (f32x4){0.f, 0.f, 0.f, 0.f};
    }
    half8 bf0, bf1;

    for (int ch = 0; ch < 40; ++ch) {
      const int kc = ch >> 1, half = ch & 1;
      __syncthreads();  // staged chunk ch visible (barrier drains vmcnt);
                        // also fences hbuf zero-init / prior-step writes
      if (ch < 39) {    // stage chunk ch+1 into the other buffer
        const f16* src = Wd + (size_t)(ch + 1) * CHB;
        f16* dst = wbuf + ((ch + 1) & 1) * CHB;
#pragma unroll
        for (int s = 0; s < 10; ++s) {
          const int mt = w * 10 + s;
          gl_lds16(src + mt * 512 + lane * 8, dst + mt * 512);
        }
      }
      if (half == 0) {  // B-fragments: batch rows (reused across both halves)
        if (kc < 10) {  // x part: direct from L2
          const f16* xp = xT + ((size_t)t * B_ + bt * 32 + lr) * HP +
                          kc * 32 + lq * 8;
          bf0 = *(const half8*)xp;
          bf1 = *(const half8*)(xp + 16 * HP);
        } else {        // h part: from block-private LDS (frag-linear)
          const int kr = kc - 10;
          bf0 = *(const half8*)(hbuf + (kr * 2 + 0) * 512 + lane * 8);
          bf1 = *(const half8*)(hbuf + (kr * 2 + 1) * 512 + lane * 8);
        }
      }
      const f16* wb = wbuf + (ch & 1) * CHB;
#pragma unroll
      for (int i = 0; i < 10; ++i) {
        const half8 af = *(const half8*)(wb + (w * 10 + i) * 512 + lane * 8);
        acc[half * 10 + i][0] = __builtin_amdgcn_mfma_f32_16x16x32_f16(
            af, bf0, acc[half * 10 + i][0], 0, 0, 0);
        acc[half * 10 + i][1] = __builtin_amdgcn_mfma_f32_16x16x32_f16(
            af, bf1, acc[half * 10 + i][1], 0, 0, 0);
      }
    }
    __syncthreads();  // all hbuf/wbuf reads done

    // Gate epilogue: lane owns (jh, b) with 4 gate-accs; c in global
    // ([d][jh][B], lanes -> consecutive b, L2-hot); h(t) into hbuf frag-order.
#pragma unroll
    for (int ii = 0; ii < 20; ++ii) {
      const int jh = (ii >= 10 ? 160 : 0) + (w * 10 + (ii % 10)) * 4 + lq;
      if (jh < H_) {
        const float4 b4 = *(const float4*)&bias[d * ND + 4 * jh];
#pragma unroll
        for (int j = 0; j < 2; ++j) {
          const int b = j * 16 + lr;
          const float zi = acc[ii][j][0] + b4.x;
          const float zf = acc[ii][j][1] + b4.y;
          const float zg = acc[ii][j][2] + b4.z;
          const float zo = acc[ii][j][3] + b4.w;
          const size_t cidx = (size_t)jh * B_ + b;
          const float co = cb[cidx];
          const float cn = sigmoid_(zf) * co + sigmoid_(zi) * tanh_fast(zg);
          const float hn = sigmoid_(zo) * tanh_fast(cn);
          cb[cidx] = cn;
          const int kcr = jh >> 5, q = (jh >> 3) & 3, e = jh & 7;
          hbuf[((kcr * 2 + j) * 64 + q * 16 + lr) * 8 + e] = (f16)hn;
        }
      }
    }
    __syncthreads();

    // hs row t: read back from hbuf as 16B chunks, coalesced-ish stores.
    {
      const int b = tid >> 3, s = tid & 7;
      f16* dst = hs + ((size_t)d * B_ + bt * 32 + b) * SB2 + (size_t)t * TR;
      for (int g = s; g < 38; g += 8) {  // 38 groups of 8 jh (300->304 w/ pad)
        const int kcr = g >> 2, q = g & 3;
        const half8 v = *(const half8*)(
            hbuf + ((kcr * 2 + (b >> 4)) * 64 + q * 16 + (b & 15)) * 8);
        *(half8*)(dst + g * 8) = v;
      }
    }
    // next step's K-loop barriers order hbuf reads after these stores
  }
}

// ---------------------------------------------------------------------------
// attn1: alpha[b][t] = softmax_t( sum_h tanh(hs0+hs1) * conv_w[h] ).
// ---------------------------------------------------------------------------
__global__ __launch_bounds__(256) void attn1(const f16* __restrict__ hs,
                                             const float* __restrict__ conv_w,
                                             float* __restrict__ alpha_g) {
  __shared__ float cw[TR];
  __shared__ float red[48];
  const int b = blockIdx.x, tid = threadIdx.x;
  const int wave = tid >> 6, lane = tid & 63;
  for (int k = tid; k < TR; k += 256) cw[k] = (k < H_) ? conv_w[k] : 0.f;
  __syncthreads();

  const half4* s0 = (const half4*)(hs + (size_t)b * SB2);
  const half4* s1 = (const half4*)(hs + (size_t)(B_ + b) * SB2);
  for (int t = wave; t < T_; t += 4) {
    const int base = t * (TR / 4);
    float p = 0.f;
    {
      half4 a = s0[base + lane], cc = s1[base + lane];
#pragma unroll
      for (int r = 0; r < 4; r++)
        p += tanh_fast((float)a[r] + (float)cc[r]) * cw[lane * 4 + r];
    }
    if (lane < 12) {
      half4 a = s0[base + 64 + lane], cc = s1[base + 64 + lane];
#pragma unroll
      for (int r = 0; r < 4; r++)
        p += tanh_fast((float)a[r] + (float)cc[r]) * cw[256 + lane * 4 + r];
    }
#pragma unroll
    for (int o = 32; o; o >>= 1) p += __shfl_down(p, o);
    if (lane == 0) red[t] = p;
  }
  __syncthreads();
  if (tid < 64) {
    float a = (tid < T_) ? red[tid] : -1e30f;
    float mx = a;
#pragma unroll
    for (int o = 32; o; o >>= 1) mx = fmaxf(mx, __shfl_xor(mx, o));
    float e = (tid < T_) ? __expf(a - mx) : 0.f;
    float s = e;
#pragma unroll
    for (int o = 32; o; o >>= 1) s += __shfl_xor(s, o);
    if (tid < T_) alpha_g[(size_t)b * 44 + tid] = e / s;
  }
}

// ---------------------------------------------------------------------------
// attn2: r = sum_t hsum*alpha; hstar = tanh(r); FC logits; softmax.
// ---------------------------------------------------------------------------
__global__ __launch_bounds__(256) void attn2(const f16* __restrict__ hs,
                                             const float* __restrict__ alpha_g,
                                             const float* __restrict__ fc_w,
                                             const float* __restrict__ fc_b,
                                             float* __restrict__ out) {
  __shared__ float al[T_];
  __shared__ float hstar[TR];
  __shared__ float lg[NC_];
  const int b = blockIdx.x, tid = threadIdx.x;
  if (tid < T_) al[tid] = alpha_g[(size_t)b * 44 + tid];
  __syncthreads();

  const f16* s0 = hs + (size_t)b * SB2;
  const f16* s1 = hs + (size_t)(B_ + b) * SB2;
  float r0 = 0.f, r1 = 0.f;
  for (int t = 0; t < T_; t++) {
    const float a = al[t];
    r0 += ((float)s0[t * TR + tid] + (float)s1[t * TR + tid]) * a;
    if (tid < 48)
      r1 += ((float)s0[t * TR + 256 + tid] + (float)s1[t * TR + 256 + tid]) * a;
  }
  hstar[tid] = tanh_fast(r0);
  if (tid < 48) hstar[256 + tid] = tanh_fast(r1);
  __syncthreads();

  const int wave = tid >> 6, lane = tid & 63;
  for (int cls = wave; cls < NC_; cls += 4) {
    float p = 0.f;
    for (int k = lane; k < H_; k += 64) p += hstar[k] * fc_w[(size_t)cls * H_ + k];
#pragma unroll
    for (int o = 32; o; o >>= 1) p += __shfl_down(p, o);
    if (lane == 0) lg[cls] = p + fc_b[cls];
  }
  __syncthreads();
  if (tid < 64) {
    float a0 = (tid < 40) ? lg[tid] : -1e30f;
    float a1 = (tid < 40) ? lg[tid + 40] : -1e30f;
    float mx = fmaxf(a0, a1);
#pragma unroll
    for (int o = 32; o; o >>= 1) mx = fmaxf(mx, __shfl_xor(mx, o));
    float e0 = (tid < 40) ? __expf(a0 - mx) : 0.f;
    float e1 = (tid < 40) ? __expf(a1 - mx) : 0.f;
    float s = e0 + e1;
#pragma unroll
    for (int o = 32; o; o >>= 1) s += __shfl_xor(s, o);
    if (tid < 40) {
      out[(size_t)b * NC_ + tid] = e0 / s;
      out[(size_t)b * NC_ + tid + 40] = e1 / s;
    }
  }
}

// ---------------------------------------------------------------------------
extern "C" void kernel_launch(void* const* d_in, const int* in_sizes, int n_in,
                              void* d_out, int out_size, void* d_ws, size_t ws_size,
                              hipStream_t stream) {
  const float* x      = (const float*)d_in[0];
  const float* w_ih   = (const float*)d_in[1];
  const float* w_hh   = (const float*)d_in[2];
  const float* b_ih   = (const float*)d_in[3];
  const float* b_hh   = (const float*)d_in[4];
  const float* conv_w = (const float*)d_in[5];
  const float* fc_w   = (const float*)d_in[6];
  const float* fc_b   = (const float*)d_in[7];
  float* out = (float*)d_out;

  // Workspace carve (~341 MB)
  char* p = (char*)d_ws;
  f16* Wp = (f16*)p;    p += (size_t)2 * 40 * CHB * sizeof(f16);       // 3.3 MB
  float* bias = (float*)p; p += (size_t)2 * ND * sizeof(float);        // 10 KB
  p = (char*)(((uintptr_t)p + 255) & ~(uintptr_t)255);
  f16* xT = (f16*)p;    p += (size_t)T_ * B_ * HP * sizeof(f16);       // 112.7 MB
  float* c = (float*)p; p += (size_t)2 * B_ * H_ * sizeof(float);      // 9.8 MB
  f16* hs = (f16*)p;    p += ((size_t)2 * B_ * SB2 + 64) * sizeof(f16);// 214.2 MB
  float* alpha_g = (float*)p; p += (size_t)B_ * 44 * sizeof(float);    // 0.72 MB

  hipMemsetAsync(c, 0, (size_t)2 * B_ * H_ * sizeof(float), stream);

  prep_weights<<<(2 * 40 * CHB + 255) / 256, 256, 0, stream>>>(
      w_ih, w_hh, b_ih, b_hh, Wp, bias);
  prep_xT<<<dim3(B_, 5), 256, 0, stream>>>(x, xT);

  // Allow 100 KB dynamic LDS (gfx950: 160 KiB/WG), then launch the
  // batch-partitioned persistent recurrence: 256 blocks, 1/CU.
  hipFuncSetAttribute((const void*)lstm_persist,
                      hipFuncAttributeMaxDynamicSharedMemorySize, SMEM_BYTES);
  lstm_persist<<<256, 256, SMEM_BYTES, stream>>>(Wp, bias, xT, c, hs);

  attn1<<<B_, 256, 0, stream>>>(hs, conv_w, alpha_g);
  attn2<<<B_, 256, 0, stream>>>(hs, alpha_g, fc_w, fc_b, out);
}